// Round 9
// baseline (12.761 us; speedup 1.0000x reference)
//
#include <hip/hip_runtime.h>

// BagOfWords: out[b][v] = count of token v in docs[b][:] / SEQ
// docs: int32 [256, 2048], out: float32 [256, 32000]
//
// R9 = software-pipelined 2-row blocks, double-buffered LDS.
// Grid 1024 = 4 blocks/CU (32 waves/CU, the R4/R8-proven residency), but
// each block now owns vocab-chunk c (VOCAB/8 = 4000 bins, 16 KB) for TWO
// consecutive rows. Pipeline per block:
//   load tA,tB -> zero(buf0) -> scatter A -> [store row0 || zero(buf1)]
//   -> scatter B -> store row1
// The store(row0) stream overlaps zero(buf1) + tB latency, roughly
// doubling the HBM-write duty cycle vs the lockstep R8 (grid==residency
// meant every block zeroed/scattered/stored in phase; write stream idled
// ~40% of the kernel).
// Kept from the record: u32 bins (u16 packing regressed R5/R7), natural
// block ids, nontemporal lane-consecutive float4 stores (R8 win).

#define VOCAB 32000
#define BATCH 256
#define SEQ   2048
#define NCHUNK 8
#define CHUNK (VOCAB / NCHUNK)   // 4000 bins -> 16000 B per buffer
#define BLK   512

typedef float f32x4 __attribute__((ext_vector_type(4)));

__global__ __launch_bounds__(BLK) void bow_hist_kernel(
    const int* __restrict__ docs, float* __restrict__ out) {
    __shared__ unsigned int bins[2][CHUNK];   // 32000 B total

    const int wg   = blockIdx.x;          // 0..1023
    const int c    = wg & (NCHUNK - 1);   // vocab chunk
    const int b0   = (wg >> 3) << 1;      // first of two rows
    const int base = c * CHUNK;
    const int tid  = threadIdx.x;

    // Issue both row loads up front; latency hides under zero/store phases.
    const int4* rA = reinterpret_cast<const int4*>(docs + (size_t)b0 * SEQ);
    const int4* rB = reinterpret_cast<const int4*>(docs + (size_t)(b0 + 1) * SEQ);
    int4 tA = rA[tid];                    // 512 int4 = whole row
    int4 tB = rB[tid];

    uint4* buf0 = reinterpret_cast<uint4*>(bins[0]);
    uint4* buf1 = reinterpret_cast<uint4*>(bins[1]);
    const float inv = 1.0f / (float)SEQ;  // exact power of two

    // zero buf0 (1000 uint4 -> 2 ragged iters)
    for (int i = tid; i < CHUNK / 4; i += BLK) buf0[i] = make_uint4(0u, 0u, 0u, 0u);
    __syncthreads();

    // scatter row A into buf0
    {
        int r;
        r = tA.x - base; if ((unsigned)r < (unsigned)CHUNK) atomicAdd(&bins[0][r], 1u);
        r = tA.y - base; if ((unsigned)r < (unsigned)CHUNK) atomicAdd(&bins[0][r], 1u);
        r = tA.z - base; if ((unsigned)r < (unsigned)CHUNK) atomicAdd(&bins[0][r], 1u);
        r = tA.w - base; if ((unsigned)r < (unsigned)CHUNK) atomicAdd(&bins[0][r], 1u);
    }
    __syncthreads();

    // store row A (reads buf0)  ||  zero buf1 (writes buf1) — independent
    {
        float* o = out + (size_t)b0 * VOCAB + base;
        for (int i = tid; i < CHUNK / 4; i += BLK) {
            uint4 u = buf0[i];
            f32x4 v;
            v.x = (float)u.x * inv;
            v.y = (float)u.y * inv;
            v.z = (float)u.z * inv;
            v.w = (float)u.w * inv;
            __builtin_nontemporal_store(v, reinterpret_cast<f32x4*>(o) + i);
        }
        for (int i = tid; i < CHUNK / 4; i += BLK) buf1[i] = make_uint4(0u, 0u, 0u, 0u);
    }
    __syncthreads();

    // scatter row B into buf1
    {
        int r;
        r = tB.x - base; if ((unsigned)r < (unsigned)CHUNK) atomicAdd(&bins[1][r], 1u);
        r = tB.y - base; if ((unsigned)r < (unsigned)CHUNK) atomicAdd(&bins[1][r], 1u);
        r = tB.z - base; if ((unsigned)r < (unsigned)CHUNK) atomicAdd(&bins[1][r], 1u);
        r = tB.w - base; if ((unsigned)r < (unsigned)CHUNK) atomicAdd(&bins[1][r], 1u);
    }
    __syncthreads();

    // store row B
    {
        float* o = out + (size_t)(b0 + 1) * VOCAB + base;
        for (int i = tid; i < CHUNK / 4; i += BLK) {
            uint4 u = buf1[i];
            f32x4 v;
            v.x = (float)u.x * inv;
            v.y = (float)u.y * inv;
            v.z = (float)u.z * inv;
            v.w = (float)u.w * inv;
            __builtin_nontemporal_store(v, reinterpret_cast<f32x4*>(o) + i);
        }
    }
}

extern "C" void kernel_launch(void* const* d_in, const int* in_sizes, int n_in,
                              void* d_out, int out_size, void* d_ws, size_t ws_size,
                              hipStream_t stream) {
    const int* docs = (const int*)d_in[0];
    float* out = (float*)d_out;
    bow_hist_kernel<<<dim3(BATCH * NCHUNK / 2), dim3(BLK), 0, stream>>>(docs, out);
}